// Round 5
// baseline (334.463 us; speedup 1.0000x reference)
//
#include <hip/hip_runtime.h>

// VQ: z [16384,512] f32, emb [8192,512] f32
// outputs (flat f32): z_q [8388608], loss [1], idx [16384], var [1]

#define BT   16384
#define DIMS 512
#define NE   8192
#define NS   4                       // n-splits
#define BN   256
#define NTPB (NE / NS / BN)          // n-passes per block = 8

// out layout (float elements)
#define LOSS_OFF 8388608
#define IDX_OFF  8388609
#define V_OFF    8404993

// ws layout (bytes)
#define BEST_OFF  0         // u64[16384]
#define ENORM_OFF 131072    // f32[8192]
#define SUMS_OFF  163840    // double[3]
#define CNT_OFF   163864    // unsigned

typedef __attribute__((ext_vector_type(8))) short short8;
typedef __attribute__((ext_vector_type(16))) float floatx16;

#define AS1(p) ((const __attribute__((address_space(1))) void*)(p))
#define AS3(p) ((__attribute__((address_space(3))) void*)(p))

__device__ __forceinline__ unsigned f2bf(float f) {
    unsigned u = __builtin_bit_cast(unsigned, f);
    u += 0x7FFFu + ((u >> 16) & 1u);          // RNE
    return u >> 16;
}

// fused prep: emb->bf16 + ||e||^2 (blocks 0..NE/4), z->bf16 (rest), init best/sums/counter
__global__ __launch_bounds__(256) void prep_kernel(
    const float* __restrict__ z, const float* __restrict__ emb,
    ushort* __restrict__ zh, ushort* __restrict__ ehh,
    float* __restrict__ enorm, unsigned long long* __restrict__ best,
    double* __restrict__ sums, unsigned* __restrict__ counter)
{
    const int lane = threadIdx.x & 63, w = threadIdx.x >> 6;
    const int b = blockIdx.x;
    if (b < NE / 4) {
        const int row = b * 4 + w;
        const float4* p = (const float4*)(emb + (size_t)row * DIMS + lane * 8);
        float4 a = p[0], bb = p[1];
        uint4 h;
        h.x = f2bf(a.x) | (f2bf(a.y) << 16);
        h.y = f2bf(a.z) | (f2bf(a.w) << 16);
        h.z = f2bf(bb.x) | (f2bf(bb.y) << 16);
        h.w = f2bf(bb.z) | (f2bf(bb.w) << 16);
        *(uint4*)(ehh + (size_t)row * DIMS + lane * 8) = h;
        float s = a.x*a.x + a.y*a.y + a.z*a.z + a.w*a.w
                + bb.x*bb.x + bb.y*bb.y + bb.z*bb.z + bb.w*bb.w;
        #pragma unroll
        for (int off = 32; off > 0; off >>= 1) s += __shfl_down(s, off, 64);
        if (lane == 0) enorm[row] = s;
    } else {
        const int row = (b - NE / 4) * 4 + w;
        const float4* p = (const float4*)(z + (size_t)row * DIMS + lane * 8);
        float4 a = p[0], bb = p[1];
        uint4 h;
        h.x = f2bf(a.x) | (f2bf(a.y) << 16);
        h.y = f2bf(a.z) | (f2bf(a.w) << 16);
        h.z = f2bf(bb.x) | (f2bf(bb.y) << 16);
        h.w = f2bf(bb.z) | (f2bf(bb.w) << 16);
        *(uint4*)(zh + (size_t)row * DIMS + lane * 8) = h;
    }
    const int gid = b * 256 + threadIdx.x;
    if (gid < BT) best[gid] = 0xFFFFFFFFFFFFFFFFULL;
    if (gid == 0) { sums[0] = 0.0; sums[1] = 0.0; sums[2] = 0.0; *counter = 0u; }
}

// bf16 MFMA argmin: score[m][n] = ||e_n||^2 - 2 z_m.e_n.
// BM=128 x BN=256 tiles, BK=64, 32x32x16 MFMA, 4 waves in 2x2 (per-wave 64x128).
// Fragment-major LDS layout: each (kk, rowblk) chunk is 64 lanes x 16B contiguous,
// so both global_load_lds writes and ds_read_b128 frag reads are conflict-free.
// Each block sweeps NTPB n-passes with running (best,idx) in registers; the
// pack/shfl/atomicMin epilogue runs once per block. Ascending-n strict-< =
// numpy first-occurrence tie-break.
__global__ __launch_bounds__(256, 2) void argmin_mfma(
    const ushort* __restrict__ zh, const ushort* __restrict__ eh,
    const float* __restrict__ enorm, unsigned long long* __restrict__ best)
{
    // A: 4 kk x 4 rowblk x 512 ushorts = 16 KB; B: 4 kk x 8 rowblk x 512 = 32 KB
    __shared__ __align__(16) ushort lds[24576];
    const int t = threadIdx.x;
    const int w = t >> 6, lane = t & 63;
    const int l31 = lane & 31, lh = lane >> 5;
    const int mt = blockIdx.x & 127, ns = blockIdx.x >> 7;
    const int m0 = mt * 128;
    const int wm = (w & 1) * 64, wn = (w >> 1) * 128;
    const int arb = (w & 1) * 2, brb = (w >> 1) * 4;

    // staging: wave w handles rowblk-groups [3w, 3w+3) of 12 (4 A + 8 B).
    // group g, kk: lane l supplies row rb*32+(l&31), elems kk*16+(l>>5)*8 .. +8
    const size_t laneoff = (size_t)l31 * DIMS + lh * 8;
    const ushort* zA = zh + (size_t)m0 * DIMS;

    float bs[32];
    int   bn_[32];
    #pragma unroll
    for (int k = 0; k < 32; k++) { bs[k] = 3.4e38f; bn_[k] = 0; }

    for (int nt = 0; nt < NTPB; nt++) {
        const int n0 = (ns * NTPB + nt) * BN;
        const ushort* eB = eh + (size_t)n0 * DIMS;

        // per-wave staging descriptors (wave-uniform except the per-lane row offset)
        const ushort* gptr[3];
        int ldsb[3], kkst[3];
        #pragma unroll
        for (int gi = 0; gi < 3; gi++) {
            const int g = w * 3 + gi;
            if (g < 4) {
                gptr[gi] = zA + (size_t)(g * 32) * DIMS + laneoff;
                ldsb[gi] = g * 512;        kkst[gi] = 4 * 512;
            } else {
                const int rb = g - 4;
                gptr[gi] = eB + (size_t)(rb * 32) * DIMS + laneoff;
                ldsb[gi] = 8192 + rb * 512; kkst[gi] = 8 * 512;
            }
        }

        floatx16 acc[2][4];
        #pragma unroll
        for (int i = 0; i < 2; i++)
            #pragma unroll
            for (int j = 0; j < 4; j++)
                #pragma unroll
                for (int r = 0; r < 16; r++) acc[i][j][r] = 0.0f;

        for (int k0 = 0; k0 < DIMS; k0 += 64) {
            __syncthreads();
            #pragma unroll
            for (int gi = 0; gi < 3; gi++)
                #pragma unroll
                for (int kk = 0; kk < 4; kk++)
                    __builtin_amdgcn_global_load_lds(AS1(gptr[gi] + k0 + kk * 16),
                                                     AS3(&lds[ldsb[gi] + kk * kkst[gi]]),
                                                     16, 0, 0);
            __syncthreads();
            #pragma unroll
            for (int kk = 0; kk < 4; kk++) {
                short8 a[2], b[4];
                #pragma unroll
                for (int i = 0; i < 2; i++)
                    a[i] = *(const short8*)&lds[(kk * 4 + arb + i) * 512 + lane * 8];
                #pragma unroll
                for (int j = 0; j < 4; j++)
                    b[j] = *(const short8*)&lds[8192 + (kk * 8 + brb + j) * 512 + lane * 8];
                #pragma unroll
                for (int i = 0; i < 2; i++)
                    #pragma unroll
                    for (int j = 0; j < 4; j++)
                        acc[i][j] = __builtin_amdgcn_mfma_f32_32x32x16_bf16(a[i], b[j], acc[i][j], 0, 0, 0);
            }
        }

        // running best update. C/D: col=lane&31, row=(r&3)+8*(r>>2)+4*(lane>>5)
        float en[4];
        #pragma unroll
        for (int j = 0; j < 4; j++) en[j] = enorm[n0 + wn + j * 32 + l31];
        #pragma unroll
        for (int i = 0; i < 2; i++)
            #pragma unroll
            for (int r = 0; r < 16; r++) {
                const int k = i * 16 + r;
                #pragma unroll
                for (int j = 0; j < 4; j++) {   // j ascending = n ascending
                    float s = fmaf(-2.0f, acc[i][j][r], en[j]);
                    if (s < bs[k]) { bs[k] = s; bn_[k] = n0 + wn + j * 32 + l31; }
                }
            }
    }

    // once per block: pack, shfl-min over the 32-lane col group, atomicMin
    #pragma unroll
    for (int i = 0; i < 2; i++)
        #pragma unroll
        for (int r = 0; r < 16; r++) {
            const int k = i * 16 + r;
            unsigned su = __builtin_bit_cast(unsigned, bs[k]);
            su = (su & 0x80000000u) ? ~su : (su | 0x80000000u);  // order-preserving
            unsigned long long key = ((unsigned long long)su << 32) | (unsigned)bn_[k];
            #pragma unroll
            for (int off = 1; off < 32; off <<= 1) {
                unsigned long long o = __shfl_xor(key, off, 64);
                key = (o < key) ? o : key;
            }
            if (l31 == 0) {
                const int m = m0 + wm + i * 32 + (r & 3) + 8 * (r >> 2) + 4 * lh;
                atomicMin(&best[m], key);
            }
        }
}

// one block per 64 rows: idx from packed keys, gather z_q, loss + idx stats;
// last block to finish runs the finalize.
__global__ __launch_bounds__(256) void gather_loss_kernel(
    const float* __restrict__ z, const float* __restrict__ emb,
    const unsigned long long* __restrict__ best,
    float* __restrict__ out, double* __restrict__ sums, unsigned* __restrict__ counter)
{
    __shared__ int sIdx[64];
    __shared__ double red[4];
    const int t = threadIdx.x;
    const int row0 = blockIdx.x * 64;
    double myIdxSum = 0.0, myIdxSq = 0.0;
    if (t < 64) {
        int row = row0 + t;
        int idx = (int)(unsigned)(best[row] & 0xFFFFFFFFULL);
        sIdx[t] = idx;
        out[IDX_OFF + row] = (float)idx;
        myIdxSum = (double)idx;
        myIdxSq = (double)idx * (double)idx;
    }
    __syncthreads();
    double acc = 0.0;
    #pragma unroll 4
    for (int i = 0; i < 32; i++) {
        int e = i * 1024 + t * 4;        // 64 rows x 512 = 32768 elems per block
        int rl = e >> 9;
        int c = e & 511;
        int idx = sIdx[rl];
        float4 zv = *(const float4*)(z + (size_t)(row0 + rl) * DIMS + c);
        float4 ev = *(const float4*)(emb + (size_t)idx * DIMS + c);
        *(float4*)(out + (size_t)(row0 + rl) * DIMS + c) = ev;  // z_q_st value == z_q
        float dx = zv.x - ev.x, dy = zv.y - ev.y;
        float dz = zv.z - ev.z, dw = zv.w - ev.w;
        acc += (double)(dx * dx + dy * dy) + (double)(dz * dz + dw * dw);
    }
    const int lane = t & 63, wv = t >> 6;
    #pragma unroll
    for (int off = 32; off > 0; off >>= 1) {
        acc      += __shfl_down(acc, off, 64);
        myIdxSum += __shfl_down(myIdxSum, off, 64);
        myIdxSq  += __shfl_down(myIdxSq, off, 64);
    }
    if (lane == 0) red[wv] = acc;
    __syncthreads();
    if (t == 0) {
        double tot = red[0] + red[1] + red[2] + red[3];
        atomicAdd(&sums[0], tot);
        atomicAdd(&sums[1], myIdxSum);   // wave 0 held all idx stats
        atomicAdd(&sums[2], myIdxSq);
        __threadfence();
        unsigned old = atomicAdd(counter, 1u);
        if (old == gridDim.x - 1) {
            __threadfence();
            double s0 = atomicAdd(&sums[0], 0.0);
            double s1 = atomicAdd(&sums[1], 0.0);
            double s2 = atomicAdd(&sums[2], 0.0);
            out[LOSS_OFF] = (float)(1.25 * s0 / (double)((size_t)BT * DIMS));
            double m = s1 / (double)BT;
            out[V_OFF] = (float)(s2 / (double)BT - m * m);
        }
    }
}

extern "C" void kernel_launch(void* const* d_in, const int* in_sizes, int n_in,
                              void* d_out, int out_size, void* d_ws, size_t ws_size,
                              hipStream_t stream) {
    const float* z = (const float*)d_in[0];
    const float* emb = (const float*)d_in[1];
    float* out = (float*)d_out;
    char* ws = (char*)d_ws;
    unsigned long long* best = (unsigned long long*)(ws + BEST_OFF);
    float* enorm  = (float*)(ws + ENORM_OFF);
    double* sums  = (double*)(ws + SUMS_OFF);
    unsigned* counter = (unsigned*)(ws + CNT_OFF);

    // bf16 scratch in the z_q region of out (fully overwritten by gather at the end)
    ushort* zh = (ushort*)out;
    ushort* ehh = zh + (size_t)BT * DIMS;

    hipLaunchKernelGGL(prep_kernel, dim3(NE / 4 + BT / 4), dim3(256), 0, stream,
                       z, emb, zh, ehh, enorm, best, sums, counter);
    hipLaunchKernelGGL(argmin_mfma, dim3(128 * NS), dim3(256), 0, stream,
                       zh, ehh, enorm, best);
    hipLaunchKernelGGL(gather_loss_kernel, dim3(BT / 64), dim3(256), 0, stream,
                       z, emb, best, out, sums, counter);
}

// Round 6
// 305.335 us; speedup vs baseline: 1.0954x; 1.0954x over previous
//
#include <hip/hip_runtime.h>

// VQ: z [16384,512] f32, emb [8192,512] f32
// outputs (flat f32): z_q [8388608], loss [1], idx [16384], var [1]

#define BT   16384
#define DIMS 512
#define NE   8192
#define NS   4                       // n-splits
#define BN   256
#define NTPB (NE / NS / BN)          // n-passes per block = 8

// out layout (float elements)
#define LOSS_OFF 8388608
#define IDX_OFF  8388609
#define V_OFF    8404993

// ws layout (bytes)
#define BEST_OFF  0         // u64[16384]
#define ENORM_OFF 131072    // f32[8192]
#define SUMS_OFF  163840    // double[3]
#define CNT_OFF   163864    // unsigned

typedef __attribute__((ext_vector_type(8))) short short8;
typedef __attribute__((ext_vector_type(16))) float floatx16;

#define AS1(p) ((const __attribute__((address_space(1))) void*)(p))
#define AS3(p) ((__attribute__((address_space(3))) void*)(p))

__device__ __forceinline__ unsigned f2bf(float f) {
    unsigned u = __builtin_bit_cast(unsigned, f);
    u += 0x7FFFu + ((u >> 16) & 1u);          // RNE
    return u >> 16;
}

// fused prep: emb->bf16 + ||e||^2 (blocks 0..NE/4), z->bf16 (rest), init best/sums/counter
__global__ __launch_bounds__(256) void prep_kernel(
    const float* __restrict__ z, const float* __restrict__ emb,
    ushort* __restrict__ zh, ushort* __restrict__ ehh,
    float* __restrict__ enorm, unsigned long long* __restrict__ best,
    double* __restrict__ sums, unsigned* __restrict__ counter)
{
    const int lane = threadIdx.x & 63, w = threadIdx.x >> 6;
    const int b = blockIdx.x;
    if (b < NE / 4) {
        const int row = b * 4 + w;
        const float4* p = (const float4*)(emb + (size_t)row * DIMS + lane * 8);
        float4 a = p[0], bb = p[1];
        uint4 h;
        h.x = f2bf(a.x) | (f2bf(a.y) << 16);
        h.y = f2bf(a.z) | (f2bf(a.w) << 16);
        h.z = f2bf(bb.x) | (f2bf(bb.y) << 16);
        h.w = f2bf(bb.z) | (f2bf(bb.w) << 16);
        *(uint4*)(ehh + (size_t)row * DIMS + lane * 8) = h;
        float s = a.x*a.x + a.y*a.y + a.z*a.z + a.w*a.w
                + bb.x*bb.x + bb.y*bb.y + bb.z*bb.z + bb.w*bb.w;
        #pragma unroll
        for (int off = 32; off > 0; off >>= 1) s += __shfl_down(s, off, 64);
        if (lane == 0) enorm[row] = s;
    } else {
        const int row = (b - NE / 4) * 4 + w;
        const float4* p = (const float4*)(z + (size_t)row * DIMS + lane * 8);
        float4 a = p[0], bb = p[1];
        uint4 h;
        h.x = f2bf(a.x) | (f2bf(a.y) << 16);
        h.y = f2bf(a.z) | (f2bf(a.w) << 16);
        h.z = f2bf(bb.x) | (f2bf(bb.y) << 16);
        h.w = f2bf(bb.z) | (f2bf(bb.w) << 16);
        *(uint4*)(zh + (size_t)row * DIMS + lane * 8) = h;
    }
    const int gid = b * 256 + threadIdx.x;
    if (gid < BT) best[gid] = 0xFFFFFFFFFFFFFFFFULL;
    if (gid == 0) { sums[0] = 0.0; sums[1] = 0.0; sums[2] = 0.0; *counter = 0u; }
}

// bf16 MFMA argmin: score[m][n] = ||e_n||^2 - 2 z_m.e_n.
// BM=128 x BN=256, BK=64, 32x32x16 MFMA, 4 waves 2x2 (per-wave 64x128).
// LDS row-major [row][64 ushorts] with XOR-swizzled 16-B chunks: staging is
// 8 rows x full 128-B lines per global_load_lds (coalesced), frag ds_read_b128
// hits all 32 banks per half-wave (round-4-proven ~0 conflicts).
// Running (best,idx) in registers across NTPB n-passes; pack/shfl/atomicMin
// once per block. Ascending-n strict-< = numpy first-occurrence tie-break.
__global__ __launch_bounds__(256, 2) void argmin_mfma(
    const ushort* __restrict__ zh, const ushort* __restrict__ eh,
    const float* __restrict__ enorm, unsigned long long* __restrict__ best)
{
    // A: 128 rows x 64 ushorts = 16 KB @0; B: 256 rows x 64 = 32 KB @8192
    __shared__ __align__(16) ushort lds[24576];
    const int t = threadIdx.x;
    const int w = t >> 6, lane = t & 63;
    const int l31 = lane & 31, lh = lane >> 5;
    const int mt = blockIdx.x & 127, ns = blockIdx.x >> 7;
    const int m0 = mt * 128;
    const int wm = (w & 1) * 64, wn = (w >> 1) * 128;
    const int arb = (w & 1) * 2, brb = (w >> 1) * 4;

    // staging: flat chunk q = w*12+gi; q<16 -> A rows [q*8,q*8+8), else B chunk q-16.
    // lane l: row +=(l>>3), physical 16B chunk (l&7) <- logical chunk (l&7)^(l>>3)
    const int l8 = lane >> 3, c8 = lane & 7;
    const size_t glane = (size_t)l8 * DIMS + (size_t)((c8 ^ l8) * 8);
    const ushort* zA = zh + (size_t)m0 * DIMS;
    size_t grow[12]; int ldso[12]; bool fromB[12];
    #pragma unroll
    for (int gi = 0; gi < 12; gi++) {
        const int q = w * 12 + gi;
        if (q < 16) { fromB[gi] = false; grow[gi] = (size_t)(q * 8) * DIMS + glane; ldso[gi] = q * 512; }
        else { const int c = q - 16; fromB[gi] = true; grow[gi] = (size_t)(c * 8) * DIMS + glane; ldso[gi] = 8192 + c * 512; }
    }

    // frag-read swizzle: physical chunk = (kk*2 + lh) ^ (l31 & 7)
    const int pxor = l31 & 7;

    float bs[32];
    int   bn_[32];
    #pragma unroll
    for (int k = 0; k < 32; k++) { bs[k] = 3.4e38f; bn_[k] = 0; }

    for (int nt = 0; nt < NTPB; nt++) {
        const int n0 = (ns * NTPB + nt) * BN;
        const ushort* eB = eh + (size_t)n0 * DIMS;

        floatx16 acc[2][4];
        #pragma unroll
        for (int i = 0; i < 2; i++)
            #pragma unroll
            for (int j = 0; j < 4; j++)
                #pragma unroll
                for (int r = 0; r < 16; r++) acc[i][j][r] = 0.0f;

        for (int k0 = 0; k0 < DIMS; k0 += 64) {
            __syncthreads();
            #pragma unroll
            for (int gi = 0; gi < 12; gi++) {
                const ushort* g = (fromB[gi] ? eB : zA) + grow[gi] + k0;
                __builtin_amdgcn_global_load_lds(AS1(g), AS3(&lds[ldso[gi]]), 16, 0, 0);
            }
            __syncthreads();
            #pragma unroll
            for (int kk = 0; kk < 4; kk++) {
                const int po = ((kk * 2 + lh) ^ pxor) * 8;
                short8 a[2], b[4];
                #pragma unroll
                for (int i = 0; i < 2; i++)
                    a[i] = *(const short8*)&lds[((arb + i) * 32 + l31) * 64 + po];
                #pragma unroll
                for (int j = 0; j < 4; j++)
                    b[j] = *(const short8*)&lds[8192 + ((brb + j) * 32 + l31) * 64 + po];
                #pragma unroll
                for (int i = 0; i < 2; i++)
                    #pragma unroll
                    for (int j = 0; j < 4; j++)
                        acc[i][j] = __builtin_amdgcn_mfma_f32_32x32x16_bf16(a[i], b[j], acc[i][j], 0, 0, 0);
            }
        }

        // running best update. C/D: col=lane&31, row=(r&3)+8*(r>>2)+4*(lane>>5)
        float en[4];
        #pragma unroll
        for (int j = 0; j < 4; j++) en[j] = enorm[n0 + wn + j * 32 + l31];
        #pragma unroll
        for (int i = 0; i < 2; i++)
            #pragma unroll
            for (int r = 0; r < 16; r++) {
                const int k = i * 16 + r;
                #pragma unroll
                for (int j = 0; j < 4; j++) {   // j ascending = n ascending
                    float s = fmaf(-2.0f, acc[i][j][r], en[j]);
                    if (s < bs[k]) { bs[k] = s; bn_[k] = n0 + wn + j * 32 + l31; }
                }
            }
    }

    // once per block: pack, shfl-min over the 32-lane col group, atomicMin
    #pragma unroll
    for (int i = 0; i < 2; i++)
        #pragma unroll
        for (int r = 0; r < 16; r++) {
            const int k = i * 16 + r;
            unsigned su = __builtin_bit_cast(unsigned, bs[k]);
            su = (su & 0x80000000u) ? ~su : (su | 0x80000000u);  // order-preserving
            unsigned long long key = ((unsigned long long)su << 32) | (unsigned)bn_[k];
            #pragma unroll
            for (int off = 1; off < 32; off <<= 1) {
                unsigned long long o = __shfl_xor(key, off, 64);
                key = (o < key) ? o : key;
            }
            if (l31 == 0) {
                const int m = m0 + wm + i * 32 + (r & 3) + 8 * (r >> 2) + 4 * lh;
                atomicMin(&best[m], key);
            }
        }
}

// one block per 64 rows: idx from packed keys, gather z_q, loss + idx stats;
// last block to finish runs the finalize.
__global__ __launch_bounds__(256) void gather_loss_kernel(
    const float* __restrict__ z, const float* __restrict__ emb,
    const unsigned long long* __restrict__ best,
    float* __restrict__ out, double* __restrict__ sums, unsigned* __restrict__ counter)
{
    __shared__ int sIdx[64];
    __shared__ double red[4];
    const int t = threadIdx.x;
    const int row0 = blockIdx.x * 64;
    double myIdxSum = 0.0, myIdxSq = 0.0;
    if (t < 64) {
        int row = row0 + t;
        int idx = (int)(unsigned)(best[row] & 0xFFFFFFFFULL);
        sIdx[t] = idx;
        out[IDX_OFF + row] = (float)idx;
        myIdxSum = (double)idx;
        myIdxSq = (double)idx * (double)idx;
    }
    __syncthreads();
    double acc = 0.0;
    #pragma unroll 4
    for (int i = 0; i < 32; i++) {
        int e = i * 1024 + t * 4;        // 64 rows x 512 = 32768 elems per block
        int rl = e >> 9;
        int c = e & 511;
        int idx = sIdx[rl];
        float4 zv = *(const float4*)(z + (size_t)(row0 + rl) * DIMS + c);
        float4 ev = *(const float4*)(emb + (size_t)idx * DIMS + c);
        *(float4*)(out + (size_t)(row0 + rl) * DIMS + c) = ev;  // z_q_st value == z_q
        float dx = zv.x - ev.x, dy = zv.y - ev.y;
        float dz = zv.z - ev.z, dw = zv.w - ev.w;
        acc += (double)(dx * dx + dy * dy) + (double)(dz * dz + dw * dw);
    }
    const int lane = t & 63, wv = t >> 6;
    #pragma unroll
    for (int off = 32; off > 0; off >>= 1) {
        acc      += __shfl_down(acc, off, 64);
        myIdxSum += __shfl_down(myIdxSum, off, 64);
        myIdxSq  += __shfl_down(myIdxSq, off, 64);
    }
    if (lane == 0) red[wv] = acc;
    __syncthreads();
    if (t == 0) {
        double tot = red[0] + red[1] + red[2] + red[3];
        atomicAdd(&sums[0], tot);
        atomicAdd(&sums[1], myIdxSum);   // wave 0 held all idx stats
        atomicAdd(&sums[2], myIdxSq);
        __threadfence();
        unsigned old = atomicAdd(counter, 1u);
        if (old == gridDim.x - 1) {
            __threadfence();
            double s0 = atomicAdd(&sums[0], 0.0);
            double s1 = atomicAdd(&sums[1], 0.0);
            double s2 = atomicAdd(&sums[2], 0.0);
            out[LOSS_OFF] = (float)(1.25 * s0 / (double)((size_t)BT * DIMS));
            double m = s1 / (double)BT;
            out[V_OFF] = (float)(s2 / (double)BT - m * m);
        }
    }
}

extern "C" void kernel_launch(void* const* d_in, const int* in_sizes, int n_in,
                              void* d_out, int out_size, void* d_ws, size_t ws_size,
                              hipStream_t stream) {
    const float* z = (const float*)d_in[0];
    const float* emb = (const float*)d_in[1];
    float* out = (float*)d_out;
    char* ws = (char*)d_ws;
    unsigned long long* best = (unsigned long long*)(ws + BEST_OFF);
    float* enorm  = (float*)(ws + ENORM_OFF);
    double* sums  = (double*)(ws + SUMS_OFF);
    unsigned* counter = (unsigned*)(ws + CNT_OFF);

    // bf16 scratch in the z_q region of out (fully overwritten by gather at the end)
    ushort* zh = (ushort*)out;
    ushort* ehh = zh + (size_t)BT * DIMS;

    hipLaunchKernelGGL(prep_kernel, dim3(NE / 4 + BT / 4), dim3(256), 0, stream,
                       z, emb, zh, ehh, enorm, best, sums, counter);
    hipLaunchKernelGGL(argmin_mfma, dim3(128 * NS), dim3(256), 0, stream,
                       zh, ehh, enorm, best);
    hipLaunchKernelGGL(gather_loss_kernel, dim3(BT / 64), dim3(256), 0, stream,
                       z, emb, best, out, sums, counter);
}

// Round 7
// 268.422 us; speedup vs baseline: 1.2460x; 1.1375x over previous
//
#include <hip/hip_runtime.h>

// VQ: z [16384,512] f32, emb [8192,512] f32
// outputs (flat f32): z_q [8388608], loss [1], idx [16384], var [1]

#define BT   16384
#define DIMS 512
#define NE   8192
#define NS   4                       // n-splits
#define BN   256
#define NTPB (NE / NS / BN)          // n-passes per block = 8

// out layout (float elements)
#define LOSS_OFF 8388608
#define IDX_OFF  8388609
#define V_OFF    8404993

// ws layout (bytes)
#define BEST_OFF  0         // u64[16384]
#define ENORM_OFF 131072    // f32[8192]
#define SUMS_OFF  163840    // double[3]
#define CNT_OFF   163864    // unsigned

typedef __attribute__((ext_vector_type(8))) short short8;
typedef __attribute__((ext_vector_type(4))) float floatx4;

#define AS1(p) ((const __attribute__((address_space(1))) void*)(p))
#define AS3(p) ((__attribute__((address_space(3))) void*)(p))

__device__ __forceinline__ unsigned f2bf(float f) {
    unsigned u = __builtin_bit_cast(unsigned, f);
    u += 0x7FFFu + ((u >> 16) & 1u);          // RNE
    return u >> 16;
}

// fused prep: emb->bf16 + ||e||^2 (blocks 0..NE/4), z->bf16 (rest), init best/sums/counter
__global__ __launch_bounds__(256) void prep_kernel(
    const float* __restrict__ z, const float* __restrict__ emb,
    ushort* __restrict__ zh, ushort* __restrict__ ehh,
    float* __restrict__ enorm, unsigned long long* __restrict__ best,
    double* __restrict__ sums, unsigned* __restrict__ counter)
{
    const int lane = threadIdx.x & 63, w = threadIdx.x >> 6;
    const int b = blockIdx.x;
    if (b < NE / 4) {
        const int row = b * 4 + w;
        const float4* p = (const float4*)(emb + (size_t)row * DIMS + lane * 8);
        float4 a = p[0], bb = p[1];
        uint4 h;
        h.x = f2bf(a.x) | (f2bf(a.y) << 16);
        h.y = f2bf(a.z) | (f2bf(a.w) << 16);
        h.z = f2bf(bb.x) | (f2bf(bb.y) << 16);
        h.w = f2bf(bb.z) | (f2bf(bb.w) << 16);
        *(uint4*)(ehh + (size_t)row * DIMS + lane * 8) = h;
        float s = a.x*a.x + a.y*a.y + a.z*a.z + a.w*a.w
                + bb.x*bb.x + bb.y*bb.y + bb.z*bb.z + bb.w*bb.w;
        #pragma unroll
        for (int off = 32; off > 0; off >>= 1) s += __shfl_down(s, off, 64);
        if (lane == 0) enorm[row] = s;
    } else {
        const int row = (b - NE / 4) * 4 + w;
        const float4* p = (const float4*)(z + (size_t)row * DIMS + lane * 8);
        float4 a = p[0], bb = p[1];
        uint4 h;
        h.x = f2bf(a.x) | (f2bf(a.y) << 16);
        h.y = f2bf(a.z) | (f2bf(a.w) << 16);
        h.z = f2bf(bb.x) | (f2bf(bb.y) << 16);
        h.w = f2bf(bb.z) | (f2bf(bb.w) << 16);
        *(uint4*)(zh + (size_t)row * DIMS + lane * 8) = h;
    }
    const int gid = b * 256 + threadIdx.x;
    if (gid < BT) best[gid] = 0xFFFFFFFFFFFFFFFFULL;
    if (gid == 0) { sums[0] = 0.0; sums[1] = 0.0; sums[2] = 0.0; *counter = 0u; }
}

// bf16 MFMA argmin: score[m][n] = ||e_n||^2 - 2 z_m.e_n.
// BM=128 x BN=256, BK=64, 16x16x32 MFMA, 4 waves 2x2 (per-wave 64x128,
// a[4] x b[8], acc 128 VGPR) -> LDS-read/MFMA cycle ratio 0.93 (was 1.24).
// LDS addressing is the round-4-proven conflict-free scheme verbatim:
// row-major [row][64 ushorts], staging lane l covers row l>>3, physical chunk
// l&7 <- logical chunk (l&7)^(l>>3); frag reads at px=(kk*4+quad)^(l15&7).
// Running (best,idx) in registers; pack/shfl/atomicMin once per block.
// Ascending-n strict-< = numpy first-occurrence tie-break.
__global__ __launch_bounds__(256, 2) void argmin_mfma(
    const ushort* __restrict__ zh, const ushort* __restrict__ eh,
    const float* __restrict__ enorm, unsigned long long* __restrict__ best)
{
    // A: 128 rows x 64 ushorts = 16 KB @0; B: 256 rows x 64 = 32 KB @8192
    __shared__ __align__(16) ushort lds[24576];
    const int t = threadIdx.x;
    const int w = t >> 6, lane = t & 63;
    const int quad = lane >> 4, l15 = lane & 15;
    const int mt = blockIdx.x & 127, ns = blockIdx.x >> 7;
    const int m0 = mt * 128;
    const int wm = (w & 1) * 64, wn = (w >> 1) * 128;

    // staging: flat chunk q = w*12+gi; q<16 -> A rows [q*8,q*8+8), else B chunk q-16.
    const int l8 = lane >> 3, c8 = lane & 7;
    const int glane = l8 * DIMS + (c8 ^ l8) * 8;
    const ushort* zA = zh + (size_t)m0 * DIMS;
    int srcoff[12], ldso[12]; bool fromB[12];
    #pragma unroll
    for (int gi = 0; gi < 12; gi++) {
        const int q = w * 12 + gi;
        if (q < 16) { fromB[gi] = false; srcoff[gi] = q * 8 * DIMS + glane; ldso[gi] = q * 512; }
        else { const int c = q - 16; fromB[gi] = true; srcoff[gi] = c * 8 * DIMS + glane; ldso[gi] = 8192 + c * 512; }
    }

    // frag-read physical chunk: (kk*4+quad) ^ (l15&7)
    const int px0 = quad ^ (l15 & 7);
    const int px1 = (4 + quad) ^ (l15 & 7);

    float bs[16];
    int   bn_[16];
    #pragma unroll
    for (int k = 0; k < 16; k++) { bs[k] = 3.4e38f; bn_[k] = 0; }

    for (int nt = 0; nt < NTPB; nt++) {
        const int n0 = (ns * NTPB + nt) * BN;
        const ushort* eB = eh + (size_t)n0 * DIMS;

        floatx4 acc[4][8];
        #pragma unroll
        for (int i = 0; i < 4; i++)
            #pragma unroll
            for (int j = 0; j < 8; j++)
                acc[i][j] = (floatx4){0.f, 0.f, 0.f, 0.f};

        for (int k0 = 0; k0 < DIMS; k0 += 64) {
            __syncthreads();
            #pragma unroll
            for (int gi = 0; gi < 12; gi++) {
                const ushort* g = (fromB[gi] ? eB : zA) + srcoff[gi] + k0;
                __builtin_amdgcn_global_load_lds(AS1(g), AS3(&lds[ldso[gi]]), 16, 0, 0);
            }
            __syncthreads();
            #pragma unroll
            for (int kk = 0; kk < 2; kk++) {
                const int po = (kk ? px1 : px0) * 8;
                short8 a[4], b[8];
                #pragma unroll
                for (int i = 0; i < 4; i++)
                    a[i] = *(const short8*)&lds[(wm + i * 16 + l15) * 64 + po];
                #pragma unroll
                for (int j = 0; j < 8; j++)
                    b[j] = *(const short8*)&lds[8192 + (wn + j * 16 + l15) * 64 + po];
                #pragma unroll
                for (int i = 0; i < 4; i++)
                    #pragma unroll
                    for (int j = 0; j < 8; j++)
                        acc[i][j] = __builtin_amdgcn_mfma_f32_16x16x32_bf16(a[i], b[j], acc[i][j], 0, 0, 0);
            }
        }

        // running best update. C/D: col=l15 (n), row=quad*4+r (m)
        #pragma unroll
        for (int j = 0; j < 8; j++) {     // j ascending = n ascending
            const int n = n0 + wn + j * 16 + l15;
            const float en = enorm[n];
            #pragma unroll
            for (int i = 0; i < 4; i++)
                #pragma unroll
                for (int r = 0; r < 4; r++) {
                    const int k = i * 4 + r;
                    float s = fmaf(-2.0f, acc[i][j][r], en);
                    if (s < bs[k]) { bs[k] = s; bn_[k] = n; }
                }
        }
    }

    // once per block: pack, shfl-min over l15 group, atomicMin across n-splits
    #pragma unroll
    for (int i = 0; i < 4; i++)
        #pragma unroll
        for (int r = 0; r < 4; r++) {
            const int k = i * 4 + r;
            unsigned su = __builtin_bit_cast(unsigned, bs[k]);
            su = (su & 0x80000000u) ? ~su : (su | 0x80000000u);  // order-preserving
            unsigned long long key = ((unsigned long long)su << 32) | (unsigned)bn_[k];
            #pragma unroll
            for (int off = 1; off < 16; off <<= 1) {
                unsigned long long o = __shfl_xor(key, off, 64);
                key = (o < key) ? o : key;
            }
            if (l15 == 0) atomicMin(&best[m0 + wm + i * 16 + quad * 4 + r], key);
        }
}

// one block per 32 rows: idx from packed keys, gather z_q, loss + idx stats;
// last block to finish runs the finalize.
__global__ __launch_bounds__(256) void gather_loss_kernel(
    const float* __restrict__ z, const float* __restrict__ emb,
    const unsigned long long* __restrict__ best,
    float* __restrict__ out, double* __restrict__ sums, unsigned* __restrict__ counter)
{
    __shared__ int sIdx[32];
    __shared__ double red[4];
    const int t = threadIdx.x;
    const int row0 = blockIdx.x * 32;
    double myIdxSum = 0.0, myIdxSq = 0.0;
    if (t < 32) {
        int row = row0 + t;
        int idx = (int)(unsigned)(best[row] & 0xFFFFFFFFULL);
        sIdx[t] = idx;
        out[IDX_OFF + row] = (float)idx;
        myIdxSum = (double)idx;
        myIdxSq = (double)idx * (double)idx;
    }
    __syncthreads();
    double acc = 0.0;
    #pragma unroll 4
    for (int i = 0; i < 16; i++) {
        int e = i * 1024 + t * 4;        // 32 rows x 512 = 16384 elems per block
        int rl = e >> 9;
        int c = e & 511;
        int idx = sIdx[rl];
        float4 zv = *(const float4*)(z + (size_t)(row0 + rl) * DIMS + c);
        float4 ev = *(const float4*)(emb + (size_t)idx * DIMS + c);
        *(float4*)(out + (size_t)(row0 + rl) * DIMS + c) = ev;  // z_q_st value == z_q
        float dx = zv.x - ev.x, dy = zv.y - ev.y;
        float dz = zv.z - ev.z, dw = zv.w - ev.w;
        acc += (double)(dx * dx + dy * dy) + (double)(dz * dz + dw * dw);
    }
    const int lane = t & 63, wv = t >> 6;
    #pragma unroll
    for (int off = 32; off > 0; off >>= 1) {
        acc      += __shfl_down(acc, off, 64);
        myIdxSum += __shfl_down(myIdxSum, off, 64);
        myIdxSq  += __shfl_down(myIdxSq, off, 64);
    }
    if (lane == 0) red[wv] = acc;
    __syncthreads();
    if (t == 0) {
        double tot = red[0] + red[1] + red[2] + red[3];
        atomicAdd(&sums[0], tot);
        atomicAdd(&sums[1], myIdxSum);   // wave 0 held all idx stats
        atomicAdd(&sums[2], myIdxSq);
        __threadfence();
        unsigned old = atomicAdd(counter, 1u);
        if (old == gridDim.x - 1) {
            __threadfence();
            double s0 = atomicAdd(&sums[0], 0.0);
            double s1 = atomicAdd(&sums[1], 0.0);
            double s2 = atomicAdd(&sums[2], 0.0);
            out[LOSS_OFF] = (float)(1.25 * s0 / (double)((size_t)BT * DIMS));
            double m = s1 / (double)BT;
            out[V_OFF] = (float)(s2 / (double)BT - m * m);
        }
    }
}

extern "C" void kernel_launch(void* const* d_in, const int* in_sizes, int n_in,
                              void* d_out, int out_size, void* d_ws, size_t ws_size,
                              hipStream_t stream) {
    const float* z = (const float*)d_in[0];
    const float* emb = (const float*)d_in[1];
    float* out = (float*)d_out;
    char* ws = (char*)d_ws;
    unsigned long long* best = (unsigned long long*)(ws + BEST_OFF);
    float* enorm  = (float*)(ws + ENORM_OFF);
    double* sums  = (double*)(ws + SUMS_OFF);
    unsigned* counter = (unsigned*)(ws + CNT_OFF);

    // bf16 scratch in the z_q region of out (fully overwritten by gather at the end)
    ushort* zh = (ushort*)out;
    ushort* ehh = zh + (size_t)BT * DIMS;

    hipLaunchKernelGGL(prep_kernel, dim3(NE / 4 + BT / 4), dim3(256), 0, stream,
                       z, emb, zh, ehh, enorm, best, sums, counter);
    hipLaunchKernelGGL(argmin_mfma, dim3(128 * NS), dim3(256), 0, stream,
                       zh, ehh, enorm, best);
    hipLaunchKernelGGL(gather_loss_kernel, dim3(BT / 32), dim3(256), 0, stream,
                       z, emb, best, out, sums, counter);
}